// Round 8
// baseline (66.401 us; speedup 1.0000x reference)
//
#include <hip/hip_runtime.h>
#include <hip/hip_bf16.h>
#include <stdint.h>

typedef __bf16 v8bf __attribute__((ext_vector_type(8)));
typedef float  v4f  __attribute__((ext_vector_type(4)));

#define LEAK 0.2f

static __device__ __forceinline__ unsigned short bf16rne(float f) {
    union { float f; uint32_t u; } v; v.f = f;
    return (unsigned short)((v.u + 0x7FFFu + ((v.u >> 16) & 1u)) >> 16);
}
static __device__ __forceinline__ float bf2f(unsigned short s) {
    union { uint32_t u; float f; } v; v.u = (uint32_t)s << 16; return v.f;
}
static __device__ __forceinline__ void gload16(const void* g, void* l) {
    __builtin_amdgcn_global_load_lds(
        (const __attribute__((address_space(1))) void*)g,
        (__attribute__((address_space(3))) void*)l, 16, 0, 0);
}

// ---------------------------------------------------------------------------
// K1: Yt[j][n*60+lt] = bf16( sum_i x[n,i]*W[i,c] ), c = j*60+lt.  (R6-proven)
// ---------------------------------------------------------------------------
__global__ __launch_bounds__(256) void k1_ygemm(const float* __restrict__ x,
                                                const float* __restrict__ W,
                                                unsigned short* __restrict__ Yt) {
    __shared__ __align__(16) char lds[24576];   // xs f32 16KB | wt bf16 8KB
    const int blk = blockIdx.x;
    const int nt = blk / 60, ct = blk % 60;
    const int n0 = nt * 64, c0 = ct * 64;
    const int t = threadIdx.x;
    const int w = t >> 6, l = t & 63;
    const int lr = l & 15, lg = l >> 4;

#pragma unroll
    for (int k = 0; k < 4; ++k) {
        const int row = k * 16 + w * 4 + lg;
        const char* src = (const char*)(x + (size_t)(n0 + row) * 64)
                          + ((lr * 16) ^ ((row & 7) << 4));
        gload16(src, lds + k * 4096 + w * 1024);
    }
#pragma unroll
    for (int r = 0; r < 4; ++r) {
        const int q = t + (r << 8);
        const int i = q >> 4;
        const int c4 = (q & 15) << 2;
        const float4 v = *reinterpret_cast<const float4*>(W + (size_t)i * 3840 + c0 + c4);
        const unsigned short b0 = bf16rne(v.x), b1 = bf16rne(v.y);
        const unsigned short b2 = bf16rne(v.z), b3 = bf16rne(v.w);
#pragma unroll
        for (int e = 0; e < 4; ++e) {
            const int c = c4 + e;
            const unsigned short bv = (e == 0) ? b0 : (e == 1) ? b1 : (e == 2) ? b2 : b3;
            *(unsigned short*)(lds + 16384 + c * 128 + ((i * 2) ^ ((c & 7) << 4))) = bv;
        }
    }
    __syncthreads();

    v4f acc[4];
#pragma unroll
    for (int jt = 0; jt < 4; ++jt) acc[jt] = (v4f){0.f, 0.f, 0.f, 0.f};

    const int ar = 16 * w + lr;
    const int sa = (ar & 7) << 4;

#pragma unroll
    for (int s = 0; s < 2; ++s) {
        const int Xf = s * 128 + lg * 32;
        const float4 x0 = *reinterpret_cast<const float4*>(lds + ar * 256 + (Xf ^ sa));
        const float4 x1 = *reinterpret_cast<const float4*>(lds + ar * 256 + ((Xf + 16) ^ sa));
        v8bf af;
        af[0] = (__bf16)x0.x; af[1] = (__bf16)x0.y;
        af[2] = (__bf16)x0.z; af[3] = (__bf16)x0.w;
        af[4] = (__bf16)x1.x; af[5] = (__bf16)x1.y;
        af[6] = (__bf16)x1.z; af[7] = (__bf16)x1.w;

#pragma unroll
        for (int jt = 0; jt < 4; ++jt) {
            const int c = jt * 16 + lr;
            const v8bf bf = *reinterpret_cast<const v8bf*>(
                lds + 16384 + c * 128 + ((s * 64 + lg * 16) ^ ((c & 7) << 4)));
            acc[jt] = __builtin_amdgcn_mfma_f32_16x16x32_bf16(af, bf, acc[jt], 0, 0, 0);
        }
    }

#pragma unroll
    for (int jt = 0; jt < 4; ++jt) {
#pragma unroll
        for (int r = 0; r < 4; ++r) {
            const int n = n0 + 16 * w + lg * 4 + r;
            const int c = c0 + jt * 16 + lr;
            const int j = c / 60, lt = c % 60;
            Yt[j * 61440 + n * 60 + lt] = bf16rne(acc[jt][r]);
        }
    }
}

// ---------------------------------------------------------------------------
// K2: split-K GEMM.  BK=64, 30 steps, 1 barrier/step, uniform vmcnt(6).
// A: reg-staged -> bf16 in LDS (2 x 8KB, XOR-swizzled ds_write, same global
//    addresses/coalescing as the R6 DMA pattern, identical RNE rounding).
// B: global_load_lds DMA, 3 x 8KB, issued post-barrier (R6-proven placement).
// LDS 40KB -> 4 blocks/CU (was 2).  Math order bit-identical to R6.
// grid 512 = 16 m-tiles * 32 k-splits, 256 threads.
// ---------------------------------------------------------------------------
__global__ __launch_bounds__(256, 4) void k2_main(const float* __restrict__ adj,
                                                  const unsigned short* __restrict__ Yt,
                                                  unsigned short* __restrict__ partial) {
    __shared__ __align__(16) char lds[40960];   // A: 2*8KB @0, B: 3*8KB @16384
    const int blk = blockIdx.x;
    const int mt = blk >> 5, ks = blk & 31;     // blk%8 == ks%8 -> Yt XCD locality
    const int m0 = mt * 64;
    const long kc0 = (long)ks * 1920;
    const int t = threadIdx.x;
    const int w = t >> 6, l = t & 63;
    const int lr = l & 15, lg = l >> 4;

    // A sources: lane (per k) reads 16B of row k*16+w*4+lg at float-col lr*4
    // (per-instruction: 4 rows x 256B contiguous — proven coalescing).
    const float* srcA[4];
#pragma unroll
    for (int k = 0; k < 4; ++k)
        srcA[k] = adj + (size_t)(m0 + k * 16 + w * 4 + lg) * 61440 + kc0 + lr * 4;
    // A LDS write offset: bf16 rows of 128B, byte (lr*8) ^ ((row&7)<<4)
    const int aw_off = (w * 4 + lg) * 128 + ((lr * 8) ^ (((w * 4 + lg) & 7) << 4));

    const char* srcB[2];
#pragma unroll
    for (int k = 0; k < 2; ++k) {
        const int row = k * 32 + w * 8 + (l >> 3);
        srcB[k] = (const char*)(Yt + (size_t)row * 61440 + kc0)
                  + (((l & 7) * 16) ^ ((row & 7) << 4));
    }

    float4 areg[2][4];   // all indices compile-time constant (rule 20)

#define ISSUE_A(pa, s) do {                                                    \
        _Pragma("unroll")                                                      \
        for (int k_ = 0; k_ < 4; ++k_)                                         \
            areg[pa][k_] = *reinterpret_cast<const float4*>(                   \
                srcA[k_] + (size_t)(s) * 64);                                  \
    } while (0)

#define ISSUE_B(pbn, s) do {                                                   \
        char* bb_ = lds + 16384 + (pbn) * 8192;                                \
        gload16(srcB[0] + (size_t)(s) * 128, bb_ + w * 1024);                  \
        gload16(srcB[1] + (size_t)(s) * 128, bb_ + 4096 + w * 1024);           \
    } while (0)

#define WRITE_A(pa) do {                                                       \
        char* ab_ = lds + (pa) * 8192;                                         \
        _Pragma("unroll")                                                      \
        for (int k_ = 0; k_ < 4; ++k_) {                                       \
            const float4 v_ = areg[pa][k_];                                    \
            uint2 p_;                                                          \
            p_.x = (uint32_t)bf16rne(v_.x) | ((uint32_t)bf16rne(v_.y) << 16);  \
            p_.y = (uint32_t)bf16rne(v_.z) | ((uint32_t)bf16rne(v_.w) << 16);  \
            *reinterpret_cast<uint2*>(ab_ + k_ * 2048 + aw_off) = p_;          \
        }                                                                      \
    } while (0)

    v4f acc[4];
#pragma unroll
    for (int jt = 0; jt < 4; ++jt) acc[jt] = (v4f){0.f, 0.f, 0.f, 0.f};

    const int ar = 16 * w + lr;
    const int sa = (ar & 7) << 4;

#define COMPUTE(pa, pb) do {                                                   \
        const char* ab = lds + (pa) * 8192;                                    \
        const char* bb = lds + 16384 + (pb) * 8192;                            \
        const v8bf af0 = *reinterpret_cast<const v8bf*>(                       \
            ab + ar * 128 + ((lg * 16) ^ sa));                                 \
        const v8bf af1 = *reinterpret_cast<const v8bf*>(                       \
            ab + ar * 128 + ((64 + lg * 16) ^ sa));                            \
        _Pragma("unroll")                                                      \
        for (int jt = 0; jt < 4; ++jt) {                                       \
            const int br = jt * 16 + lr;                                       \
            const int sb = (br & 7) << 4;                                      \
            const v8bf b0 = *reinterpret_cast<const v8bf*>(                    \
                bb + br * 128 + ((lg * 16) ^ sb));                             \
            const v8bf b1 = *reinterpret_cast<const v8bf*>(                    \
                bb + br * 128 + ((64 + lg * 16) ^ sb));                        \
            acc[jt] = __builtin_amdgcn_mfma_f32_16x16x32_bf16(af0, b0,         \
                                                              acc[jt], 0,0,0); \
            acc[jt] = __builtin_amdgcn_mfma_f32_16x16x32_bf16(af1, b1,         \
                                                              acc[jt], 0,0,0); \
        }                                                                      \
    } while (0)

#define STEP(pa, pb, pbn, snext, doissue) do {                                 \
        asm volatile("s_waitcnt vmcnt(6)" ::: "memory");                       \
        WRITE_A(pa);                                                           \
        if (doissue) ISSUE_A(pa, snext);                                       \
        asm volatile("s_waitcnt lgkmcnt(0)" ::: "memory");                     \
        __builtin_amdgcn_s_barrier();                                          \
        asm volatile("" ::: "memory");                                         \
        if (doissue) ISSUE_B(pbn, snext);                                      \
        COMPUTE(pa, pb);                                                       \
    } while (0)

    // prologue (order A0,B0,A1,B1 so vmcnt(6) covers A0+B0 at step 0)
    ISSUE_A(0, 0); ISSUE_B(0, 0); ISSUE_A(1, 1); ISSUE_B(1, 1);

    // steps 0..23 (period lcm(2,3)=6; all buffer indices static)
#pragma unroll 1
    for (int ii = 0; ii < 4; ++ii) {
        const int ib = ii * 6;
#pragma unroll
        for (int u = 0; u < 6; ++u)
            STEP(u & 1, u % 3, (u + 2) % 3, ib + u + 2, true);
    }
    // tail: i = 24..29
    STEP(0, 0, 2, 26, true);
    STEP(1, 1, 0, 27, true);
    STEP(0, 2, 1, 28, true);
    STEP(1, 0, 2, 29, true);
    STEP(0, 1, 0, 0, false);               // i=28 (outstanding = A29+B29 = 6)
    {                                      // i=29
        asm volatile("s_waitcnt vmcnt(0)" ::: "memory");
        WRITE_A(1);
        asm volatile("s_waitcnt lgkmcnt(0)" ::: "memory");
        __builtin_amdgcn_s_barrier();
        asm volatile("" ::: "memory");
        COMPUTE(1, 2);
    }

#undef STEP
#undef COMPUTE
#undef WRITE_A
#undef ISSUE_B
#undef ISSUE_A

    unsigned short* const p = partial + (size_t)ks * 65536;
#pragma unroll
    for (int jt = 0; jt < 4; ++jt) {
#pragma unroll
        for (int r = 0; r < 4; ++r) {
            const int m = m0 + 16 * w + lg * 4 + r;
            const int j = jt * 16 + lr;
            p[m * 64 + j] = bf16rne(acc[jt][r]);
        }
    }
}

// ---------------------------------------------------------------------------
// K3: out = lrelu( sum_splits partial(bf16) + x @ W2 ).  (R6-proven)
// ---------------------------------------------------------------------------
__global__ __launch_bounds__(256) void k3_epi(const unsigned short* __restrict__ partial,
                                              const float* __restrict__ x,
                                              const float* __restrict__ W2,
                                              float* __restrict__ out) {
    const int idx = blockIdx.x * 256 + threadIdx.x;   // 0..16383
    const int m = idx >> 4;
    const int j0 = (idx & 15) * 4;

    float a0 = 0.f, a1 = 0.f, a2 = 0.f, a3 = 0.f;
#pragma unroll 8
    for (int sp = 0; sp < 32; ++sp) {
        const uint2 a = *reinterpret_cast<const uint2*>(
            partial + (size_t)sp * 65536 + m * 64 + j0);
        a0 += bf2f((unsigned short)(a.x & 0xffff));
        a1 += bf2f((unsigned short)(a.x >> 16));
        a2 += bf2f((unsigned short)(a.y & 0xffff));
        a3 += bf2f((unsigned short)(a.y >> 16));
    }

    const float* xrow = x + m * 64;
#pragma unroll 8
    for (int i = 0; i < 64; ++i) {
        const float xv = xrow[i];
        const float4 wv = *reinterpret_cast<const float4*>(W2 + i * 64 + j0);
        a0 += xv * wv.x; a1 += xv * wv.y;
        a2 += xv * wv.z; a3 += xv * wv.w;
    }

    float4 o;
    o.x = fmaxf(a0, LEAK * a0);
    o.y = fmaxf(a1, LEAK * a1);
    o.z = fmaxf(a2, LEAK * a2);
    o.w = fmaxf(a3, LEAK * a3);
    *reinterpret_cast<float4*>(out + m * 64 + j0) = o;
}

// ---------------------------------------------------------------------------
extern "C" void kernel_launch(void* const* d_in, const int* in_sizes, int n_in,
                              void* d_out, int out_size, void* d_ws, size_t ws_size,
                              hipStream_t stream) {
    const float* x   = (const float*)d_in[0];
    const float* adj = (const float*)d_in[1];
    const float* W   = (const float*)d_in[2];
    const float* W2  = (const float*)d_in[3];
    float* out = (float*)d_out;

    char* ws = (char*)d_ws;
    unsigned short* Yt      = (unsigned short*)ws;               // 7,864,320 B
    unsigned short* partial = (unsigned short*)(ws + 7864320);   // 4,194,304 B

    k1_ygemm<<<960, 256, 0, stream>>>(x, W, Yt);
    k2_main <<<512, 256, 0, stream>>>(adj, Yt, partial);
    k3_epi  <<<64,  256, 0, stream>>>(partial, x, W2, out);
}

// Round 9
// 55.126 us; speedup vs baseline: 1.2045x; 1.2045x over previous
//
#include <hip/hip_runtime.h>
#include <hip/hip_bf16.h>
#include <stdint.h>

typedef __bf16 v8bf __attribute__((ext_vector_type(8)));
typedef float  v4f  __attribute__((ext_vector_type(4)));

#define LEAK 0.2f

static __device__ __forceinline__ unsigned short bf16rne(float f) {
    union { float f; uint32_t u; } v; v.f = f;
    return (unsigned short)((v.u + 0x7FFFu + ((v.u >> 16) & 1u)) >> 16);
}
static __device__ __forceinline__ float bf2f(unsigned short s) {
    union { uint32_t u; float f; } v; v.u = (uint32_t)s << 16; return v.f;
}
static __device__ __forceinline__ void gload16(const void* g, void* l) {
    __builtin_amdgcn_global_load_lds(
        (const __attribute__((address_space(1))) void*)g,
        (__attribute__((address_space(3))) void*)l, 16, 0, 0);
}

// ---------------------------------------------------------------------------
// K1: Yt[j][n*60+lt] = bf16( sum_i x[n,i]*W[i,c] ), c = j*60+lt.  (R6-proven)
// x-slab staged via DMA (pre-swizzled source); W transposed to bf16 in LDS
// via reg-staging; B-fragment = single ds_read_b128.
// ---------------------------------------------------------------------------
__global__ __launch_bounds__(256) void k1_ygemm(const float* __restrict__ x,
                                                const float* __restrict__ W,
                                                unsigned short* __restrict__ Yt) {
    __shared__ __align__(16) char lds[24576];   // xs f32 16KB | wt bf16 8KB
    const int blk = blockIdx.x;
    const int nt = blk / 60, ct = blk % 60;
    const int n0 = nt * 64, c0 = ct * 64;
    const int t = threadIdx.x;
    const int w = t >> 6, l = t & 63;
    const int lr = l & 15, lg = l >> 4;

#pragma unroll
    for (int k = 0; k < 4; ++k) {
        const int row = k * 16 + w * 4 + lg;
        const char* src = (const char*)(x + (size_t)(n0 + row) * 64)
                          + ((lr * 16) ^ ((row & 7) << 4));
        gload16(src, lds + k * 4096 + w * 1024);
    }
#pragma unroll
    for (int r = 0; r < 4; ++r) {
        const int q = t + (r << 8);
        const int i = q >> 4;
        const int c4 = (q & 15) << 2;
        const float4 v = *reinterpret_cast<const float4*>(W + (size_t)i * 3840 + c0 + c4);
        const unsigned short b0 = bf16rne(v.x), b1 = bf16rne(v.y);
        const unsigned short b2 = bf16rne(v.z), b3 = bf16rne(v.w);
#pragma unroll
        for (int e = 0; e < 4; ++e) {
            const int c = c4 + e;
            const unsigned short bv = (e == 0) ? b0 : (e == 1) ? b1 : (e == 2) ? b2 : b3;
            *(unsigned short*)(lds + 16384 + c * 128 + ((i * 2) ^ ((c & 7) << 4))) = bv;
        }
    }
    __syncthreads();

    v4f acc[4];
#pragma unroll
    for (int jt = 0; jt < 4; ++jt) acc[jt] = (v4f){0.f, 0.f, 0.f, 0.f};

    const int ar = 16 * w + lr;
    const int sa = (ar & 7) << 4;

#pragma unroll
    for (int s = 0; s < 2; ++s) {
        const int Xf = s * 128 + lg * 32;
        const float4 x0 = *reinterpret_cast<const float4*>(lds + ar * 256 + (Xf ^ sa));
        const float4 x1 = *reinterpret_cast<const float4*>(lds + ar * 256 + ((Xf + 16) ^ sa));
        v8bf af;
        af[0] = (__bf16)x0.x; af[1] = (__bf16)x0.y;
        af[2] = (__bf16)x0.z; af[3] = (__bf16)x0.w;
        af[4] = (__bf16)x1.x; af[5] = (__bf16)x1.y;
        af[6] = (__bf16)x1.z; af[7] = (__bf16)x1.w;

#pragma unroll
        for (int jt = 0; jt < 4; ++jt) {
            const int c = jt * 16 + lr;
            const v8bf bf = *reinterpret_cast<const v8bf*>(
                lds + 16384 + c * 128 + ((s * 64 + lg * 16) ^ ((c & 7) << 4)));
            acc[jt] = __builtin_amdgcn_mfma_f32_16x16x32_bf16(af, bf, acc[jt], 0, 0, 0);
        }
    }

#pragma unroll
    for (int jt = 0; jt < 4; ++jt) {
#pragma unroll
        for (int r = 0; r < 4; ++r) {
            const int n = n0 + 16 * w + lg * 4 + r;
            const int c = c0 + jt * 16 + lr;
            const int j = c / 60, lt = c % 60;
            Yt[j * 61440 + n * 60 + lt] = bf16rne(acc[jt][r]);
        }
    }
}

// ---------------------------------------------------------------------------
// K2: split-K GEMM, 3-buffer 2-deep counted-vmcnt DMA pipeline (R6-proven,
// byte-identical revert).  bf16 partial stores.
// partial[ks][m][j] = bf16( sum_{k in 1920-chunk} adj[m][k]*Yt[j][k] )
// grid 512 = 16 m-tiles * 32 k-splits, 256 threads, 30 BK=64 steps.
// R7 (BK=32 deep pipeline) and R8 (reg-staged A, 4 blocks/CU) both regressed:
// this structure is a measured local optimum.
// ---------------------------------------------------------------------------
__global__ __launch_bounds__(256) void k2_main(const float* __restrict__ adj,
                                               const unsigned short* __restrict__ Yt,
                                               unsigned short* __restrict__ partial) {
    __shared__ __align__(16) char lds[73728];
    const int blk = blockIdx.x;
    const int mt = blk >> 5, ks = blk & 31;      // blk%8 == ks%8 -> Yt XCD locality
    const int m0 = mt * 64;
    const long kc0 = (long)ks * 1920;
    const int t = threadIdx.x;
    const int w = t >> 6, l = t & 63;
    const int lr = l & 15, lg = l >> 4;

    const char* srcA[4];
    const char* srcB[2];
#pragma unroll
    for (int k = 0; k < 4; ++k) {
        const int row = k * 16 + w * 4 + lg;
        srcA[k] = (const char*)(adj + (size_t)(m0 + row) * 61440 + kc0)
                  + ((lr * 16) ^ ((row & 7) << 4));
    }
#pragma unroll
    for (int k = 0; k < 2; ++k) {
        const int row = k * 32 + w * 8 + (l >> 3);
        srcB[k] = (const char*)(Yt + (size_t)row * 61440 + kc0)
                  + (((l & 7) * 16) ^ ((row & 7) << 4));
    }

#define STAGE(bs, s) do {                                                      \
        char* ab_ = lds + (bs) * 16384;                                        \
        char* bb_ = lds + 49152 + (bs) * 8192;                                 \
        _Pragma("unroll")                                                      \
        for (int k_ = 0; k_ < 4; ++k_)                                         \
            gload16(srcA[k_] + (size_t)(s) * 256, ab_ + k_ * 4096 + w * 1024); \
        _Pragma("unroll")                                                      \
        for (int k_ = 0; k_ < 2; ++k_)                                         \
            gload16(srcB[k_] + (size_t)(s) * 128, bb_ + k_ * 4096 + w * 1024); \
    } while (0)

    v4f acc[4];
#pragma unroll
    for (int jt = 0; jt < 4; ++jt) acc[jt] = (v4f){0.f, 0.f, 0.f, 0.f};

    const int ar = 16 * w + lr;
    const int sa = (ar & 7) << 4;

    STAGE(0, 0);
    STAGE(1, 1);
    int bs = 2, bc = 0;

#pragma unroll 1
    for (int i = 0; i < 30; ++i) {
        if (i < 29) { asm volatile("s_waitcnt vmcnt(6)" ::: "memory"); }
        else        { asm volatile("s_waitcnt vmcnt(0)" ::: "memory"); }
        __builtin_amdgcn_s_barrier();
        asm volatile("" ::: "memory");
        if (i < 28) STAGE(bs, i + 2);

        const char* ab = lds + bc * 16384;
        const char* bb = lds + 49152 + bc * 8192;
        v8bf af[2];
#pragma unroll
        for (int ss = 0; ss < 2; ++ss) {
            const int Xf = ss * 128 + lg * 32;
            const float4 x0 = *reinterpret_cast<const float4*>(ab + ar * 256 + (Xf ^ sa));
            const float4 x1 = *reinterpret_cast<const float4*>(ab + ar * 256 + ((Xf + 16) ^ sa));
            v8bf f;
            f[0] = (__bf16)x0.x; f[1] = (__bf16)x0.y;
            f[2] = (__bf16)x0.z; f[3] = (__bf16)x0.w;
            f[4] = (__bf16)x1.x; f[5] = (__bf16)x1.y;
            f[6] = (__bf16)x1.z; f[7] = (__bf16)x1.w;
            af[ss] = f;
        }
#pragma unroll
        for (int jt = 0; jt < 4; ++jt) {
            const int br = 16 * jt + lr;
            const int sb = (br & 7) << 4;
            const v8bf b0 = *reinterpret_cast<const v8bf*>(bb + br * 128 + ((lg * 16) ^ sb));
            const v8bf b1 = *reinterpret_cast<const v8bf*>(bb + br * 128 + ((64 + lg * 16) ^ sb));
            acc[jt] = __builtin_amdgcn_mfma_f32_16x16x32_bf16(af[0], b0, acc[jt], 0, 0, 0);
            acc[jt] = __builtin_amdgcn_mfma_f32_16x16x32_bf16(af[1], b1, acc[jt], 0, 0, 0);
        }

        bs = (bs == 2) ? 0 : bs + 1;
        bc = (bc == 2) ? 0 : bc + 1;
    }
#undef STAGE

    unsigned short* const p = partial + (size_t)ks * 65536;
#pragma unroll
    for (int jt = 0; jt < 4; ++jt) {
#pragma unroll
        for (int r = 0; r < 4; ++r) {
            const int m = m0 + 16 * w + lg * 4 + r;
            const int j = jt * 16 + lr;
            p[m * 64 + j] = bf16rne(acc[jt][r]);
        }
    }
}

// ---------------------------------------------------------------------------
// K3: out = lrelu( sum_splits partial(bf16) + x @ W2 ).  (R6-proven)
// 16384 threads (64 blocks); each handles one m and 4 j's; fully coalesced.
// ---------------------------------------------------------------------------
__global__ __launch_bounds__(256) void k3_epi(const unsigned short* __restrict__ partial,
                                              const float* __restrict__ x,
                                              const float* __restrict__ W2,
                                              float* __restrict__ out) {
    const int idx = blockIdx.x * 256 + threadIdx.x;   // 0..16383
    const int m = idx >> 4;
    const int j0 = (idx & 15) * 4;

    float a0 = 0.f, a1 = 0.f, a2 = 0.f, a3 = 0.f;
#pragma unroll 8
    for (int sp = 0; sp < 32; ++sp) {
        const uint2 a = *reinterpret_cast<const uint2*>(
            partial + (size_t)sp * 65536 + m * 64 + j0);
        a0 += bf2f((unsigned short)(a.x & 0xffff));
        a1 += bf2f((unsigned short)(a.x >> 16));
        a2 += bf2f((unsigned short)(a.y & 0xffff));
        a3 += bf2f((unsigned short)(a.y >> 16));
    }

    const float* xrow = x + m * 64;
#pragma unroll 8
    for (int i = 0; i < 64; ++i) {
        const float xv = xrow[i];
        const float4 wv = *reinterpret_cast<const float4*>(W2 + i * 64 + j0);
        a0 += xv * wv.x; a1 += xv * wv.y;
        a2 += xv * wv.z; a3 += xv * wv.w;
    }

    float4 o;
    o.x = fmaxf(a0, LEAK * a0);
    o.y = fmaxf(a1, LEAK * a1);
    o.z = fmaxf(a2, LEAK * a2);
    o.w = fmaxf(a3, LEAK * a3);
    *reinterpret_cast<float4*>(out + m * 64 + j0) = o;
}

// ---------------------------------------------------------------------------
extern "C" void kernel_launch(void* const* d_in, const int* in_sizes, int n_in,
                              void* d_out, int out_size, void* d_ws, size_t ws_size,
                              hipStream_t stream) {
    const float* x   = (const float*)d_in[0];
    const float* adj = (const float*)d_in[1];
    const float* W   = (const float*)d_in[2];
    const float* W2  = (const float*)d_in[3];
    float* out = (float*)d_out;

    char* ws = (char*)d_ws;
    unsigned short* Yt      = (unsigned short*)ws;               // 7,864,320 B
    unsigned short* partial = (unsigned short*)(ws + 7864320);   // 4,194,304 B

    k1_ygemm<<<960, 256, 0, stream>>>(x, W, Yt);
    k2_main <<<512, 256, 0, stream>>>(adj, Yt, partial);
    k3_epi  <<<64,  256, 0, stream>>>(partial, x, W2, out);
}

// Round 10
// 54.881 us; speedup vs baseline: 1.2099x; 1.0045x over previous
//
#include <hip/hip_runtime.h>
#include <hip/hip_bf16.h>
#include <stdint.h>

typedef __bf16 v8bf __attribute__((ext_vector_type(8)));
typedef float  v4f  __attribute__((ext_vector_type(4)));

#define LEAK 0.2f

static __device__ __forceinline__ unsigned short bf16rne(float f) {
    union { float f; uint32_t u; } v; v.f = f;
    return (unsigned short)((v.u + 0x7FFFu + ((v.u >> 16) & 1u)) >> 16);
}
static __device__ __forceinline__ float bf2f(unsigned short s) {
    union { uint32_t u; float f; } v; v.u = (uint32_t)s << 16; return v.f;
}
static __device__ __forceinline__ void gload16(const void* g, void* l) {
    __builtin_amdgcn_global_load_lds(
        (const __attribute__((address_space(1))) void*)g,
        (__attribute__((address_space(3))) void*)l, 16, 0, 0);
}

// ---------------------------------------------------------------------------
// K1: Yt[j][n*60+lt] = bf16( sum_i x[n,i]*W[i,c] ), c = j*60+lt.  (R6-proven)
// ---------------------------------------------------------------------------
__global__ __launch_bounds__(256) void k1_ygemm(const float* __restrict__ x,
                                                const float* __restrict__ W,
                                                unsigned short* __restrict__ Yt) {
    __shared__ __align__(16) char lds[24576];   // xs f32 16KB | wt bf16 8KB
    const int blk = blockIdx.x;
    const int nt = blk / 60, ct = blk % 60;
    const int n0 = nt * 64, c0 = ct * 64;
    const int t = threadIdx.x;
    const int w = t >> 6, l = t & 63;
    const int lr = l & 15, lg = l >> 4;

#pragma unroll
    for (int k = 0; k < 4; ++k) {
        const int row = k * 16 + w * 4 + lg;
        const char* src = (const char*)(x + (size_t)(n0 + row) * 64)
                          + ((lr * 16) ^ ((row & 7) << 4));
        gload16(src, lds + k * 4096 + w * 1024);
    }
#pragma unroll
    for (int r = 0; r < 4; ++r) {
        const int q = t + (r << 8);
        const int i = q >> 4;
        const int c4 = (q & 15) << 2;
        const float4 v = *reinterpret_cast<const float4*>(W + (size_t)i * 3840 + c0 + c4);
        const unsigned short b0 = bf16rne(v.x), b1 = bf16rne(v.y);
        const unsigned short b2 = bf16rne(v.z), b3 = bf16rne(v.w);
#pragma unroll
        for (int e = 0; e < 4; ++e) {
            const int c = c4 + e;
            const unsigned short bv = (e == 0) ? b0 : (e == 1) ? b1 : (e == 2) ? b2 : b3;
            *(unsigned short*)(lds + 16384 + c * 128 + ((i * 2) ^ ((c & 7) << 4))) = bv;
        }
    }
    __syncthreads();

    v4f acc[4];
#pragma unroll
    for (int jt = 0; jt < 4; ++jt) acc[jt] = (v4f){0.f, 0.f, 0.f, 0.f};

    const int ar = 16 * w + lr;
    const int sa = (ar & 7) << 4;

#pragma unroll
    for (int s = 0; s < 2; ++s) {
        const int Xf = s * 128 + lg * 32;
        const float4 x0 = *reinterpret_cast<const float4*>(lds + ar * 256 + (Xf ^ sa));
        const float4 x1 = *reinterpret_cast<const float4*>(lds + ar * 256 + ((Xf + 16) ^ sa));
        v8bf af;
        af[0] = (__bf16)x0.x; af[1] = (__bf16)x0.y;
        af[2] = (__bf16)x0.z; af[3] = (__bf16)x0.w;
        af[4] = (__bf16)x1.x; af[5] = (__bf16)x1.y;
        af[6] = (__bf16)x1.z; af[7] = (__bf16)x1.w;

#pragma unroll
        for (int jt = 0; jt < 4; ++jt) {
            const int c = jt * 16 + lr;
            const v8bf bf = *reinterpret_cast<const v8bf*>(
                lds + 16384 + c * 128 + ((s * 64 + lg * 16) ^ ((c & 7) << 4)));
            acc[jt] = __builtin_amdgcn_mfma_f32_16x16x32_bf16(af, bf, acc[jt], 0, 0, 0);
        }
    }

#pragma unroll
    for (int jt = 0; jt < 4; ++jt) {
#pragma unroll
        for (int r = 0; r < 4; ++r) {
            const int n = n0 + 16 * w + lg * 4 + r;
            const int c = c0 + jt * 16 + lr;
            const int j = c / 60, lt = c % 60;
            Yt[j * 61440 + n * 60 + lt] = bf16rne(acc[jt][r]);
        }
    }
}

// ---------------------------------------------------------------------------
// K2: split-K GEMM, 512-THREAD variant of the R6-proven pipeline.
// Same 64x64 tile, same 72KB 3-buffer DMA staging, same 30 BK=64 steps, same
// counted-vmcnt (now 3 loads/wave/stage -> vmcnt(3)), same math order
// (bit-identical output).  8 waves/block x 2 blocks/CU = 4 waves/SIMD (2x R6)
// for latency hiding across the barrier lockstep.
// Wave w: A row-tile (w&3), j-tiles {2*(w>>2), 2*(w>>2)+1}; 2 acc tiles.
// Staging per wave/stage: 2x A gload16 (rows (2w+k)*4+(l>>4)) + 1x B gload16
// (rows 8w+(l>>3)); layout invariant LDS[row,X]=global[row,X^((row&7)<<4)].
// grid 512 = 16 m-tiles * 32 k-splits (blk%8==ks%8 -> Yt XCD locality).
// ---------------------------------------------------------------------------
__global__ __launch_bounds__(512, 4) void k2_main(const float* __restrict__ adj,
                                                  const unsigned short* __restrict__ Yt,
                                                  unsigned short* __restrict__ partial) {
    __shared__ __align__(16) char lds[73728];   // A: 3*16KB @0, B: 3*8KB @49152
    const int blk = blockIdx.x;
    const int mt = blk >> 5, ks = blk & 31;
    const int m0 = mt * 64;
    const long kc0 = (long)ks * 1920;
    const int t = threadIdx.x;
    const int w = t >> 6, l = t & 63;          // w = 0..7
    const int lr = l & 15, lg = l >> 4;

    // A staging sources: wave w, load k: row (w*2+k)*4 + (l>>4)
    const char* srcA[2];
#pragma unroll
    for (int k = 0; k < 2; ++k) {
        const int row = (w * 2 + k) * 4 + (l >> 4);
        srcA[k] = (const char*)(adj + (size_t)(m0 + row) * 61440 + kc0)
                  + ((lr * 16) ^ ((row & 7) << 4));
    }
    // B staging source: wave w: row w*8 + (l>>3)
    const char* srcB;
    {
        const int row = w * 8 + (l >> 3);
        srcB = (const char*)(Yt + (size_t)row * 61440 + kc0)
               + (((l & 7) * 16) ^ ((row & 7) << 4));
    }

#define STAGE(bsx, s) do {                                                \
        char* ab_ = lds + (bsx) * 16384;                                  \
        char* bb_ = lds + 49152 + (bsx) * 8192;                           \
        gload16(srcA[0] + (size_t)(s) * 256, ab_ + (w * 2) * 1024);       \
        gload16(srcA[1] + (size_t)(s) * 256, ab_ + (w * 2 + 1) * 1024);   \
        gload16(srcB + (size_t)(s) * 128, bb_ + w * 1024);                \
    } while (0)

    v4f acc[2];
    acc[0] = (v4f){0.f, 0.f, 0.f, 0.f};
    acc[1] = (v4f){0.f, 0.f, 0.f, 0.f};

    const int aw = w & 3, jt0 = (w >> 2) * 2;
    const int ar = 16 * aw + lr;
    const int sa = (ar & 7) << 4;

    STAGE(0, 0);
    STAGE(1, 1);
    int bs = 2, bc = 0;

#pragma unroll 1
    for (int i = 0; i < 30; ++i) {
        if (i < 29) { asm volatile("s_waitcnt vmcnt(3)" ::: "memory"); }
        else        { asm volatile("s_waitcnt vmcnt(0)" ::: "memory"); }
        __builtin_amdgcn_s_barrier();
        asm volatile("" ::: "memory");
        if (i < 28) STAGE(bs, i + 2);

        const char* ab = lds + bc * 16384;
        const char* bb = lds + 49152 + bc * 8192;
        v8bf af[2];
#pragma unroll
        for (int ss = 0; ss < 2; ++ss) {
            const int Xf = ss * 128 + lg * 32;
            const float4 x0 = *reinterpret_cast<const float4*>(ab + ar * 256 + (Xf ^ sa));
            const float4 x1 = *reinterpret_cast<const float4*>(ab + ar * 256 + ((Xf + 16) ^ sa));
            v8bf f;
            f[0] = (__bf16)x0.x; f[1] = (__bf16)x0.y;
            f[2] = (__bf16)x0.z; f[3] = (__bf16)x0.w;
            f[4] = (__bf16)x1.x; f[5] = (__bf16)x1.y;
            f[6] = (__bf16)x1.z; f[7] = (__bf16)x1.w;
            af[ss] = f;
        }
#pragma unroll
        for (int u = 0; u < 2; ++u) {
            const int br = (jt0 + u) * 16 + lr;
            const int sb = (br & 7) << 4;
            const v8bf b0 = *reinterpret_cast<const v8bf*>(bb + br * 128 + ((lg * 16) ^ sb));
            const v8bf b1 = *reinterpret_cast<const v8bf*>(bb + br * 128 + ((64 + lg * 16) ^ sb));
            acc[u] = __builtin_amdgcn_mfma_f32_16x16x32_bf16(af[0], b0, acc[u], 0, 0, 0);
            acc[u] = __builtin_amdgcn_mfma_f32_16x16x32_bf16(af[1], b1, acc[u], 0, 0, 0);
        }

        bs = (bs == 2) ? 0 : bs + 1;
        bc = (bc == 2) ? 0 : bc + 1;
    }
#undef STAGE

    unsigned short* const p = partial + (size_t)ks * 65536;
#pragma unroll
    for (int u = 0; u < 2; ++u) {
#pragma unroll
        for (int r = 0; r < 4; ++r) {
            const int m = m0 + 16 * aw + lg * 4 + r;
            const int j = (jt0 + u) * 16 + lr;
            p[m * 64 + j] = bf16rne(acc[u][r]);
        }
    }
}

// ---------------------------------------------------------------------------
// K3: out = lrelu( sum_splits partial(bf16) + x @ W2 ).  (R6-proven)
// ---------------------------------------------------------------------------
__global__ __launch_bounds__(256) void k3_epi(const unsigned short* __restrict__ partial,
                                              const float* __restrict__ x,
                                              const float* __restrict__ W2,
                                              float* __restrict__ out) {
    const int idx = blockIdx.x * 256 + threadIdx.x;   // 0..16383
    const int m = idx >> 4;
    const int j0 = (idx & 15) * 4;

    float a0 = 0.f, a1 = 0.f, a2 = 0.f, a3 = 0.f;
#pragma unroll 8
    for (int sp = 0; sp < 32; ++sp) {
        const uint2 a = *reinterpret_cast<const uint2*>(
            partial + (size_t)sp * 65536 + m * 64 + j0);
        a0 += bf2f((unsigned short)(a.x & 0xffff));
        a1 += bf2f((unsigned short)(a.x >> 16));
        a2 += bf2f((unsigned short)(a.y & 0xffff));
        a3 += bf2f((unsigned short)(a.y >> 16));
    }

    const float* xrow = x + m * 64;
#pragma unroll 8
    for (int i = 0; i < 64; ++i) {
        const float xv = xrow[i];
        const float4 wv = *reinterpret_cast<const float4*>(W2 + i * 64 + j0);
        a0 += xv * wv.x; a1 += xv * wv.y;
        a2 += xv * wv.z; a3 += xv * wv.w;
    }

    float4 o;
    o.x = fmaxf(a0, LEAK * a0);
    o.y = fmaxf(a1, LEAK * a1);
    o.z = fmaxf(a2, LEAK * a2);
    o.w = fmaxf(a3, LEAK * a3);
    *reinterpret_cast<float4*>(out + m * 64 + j0) = o;
}

// ---------------------------------------------------------------------------
extern "C" void kernel_launch(void* const* d_in, const int* in_sizes, int n_in,
                              void* d_out, int out_size, void* d_ws, size_t ws_size,
                              hipStream_t stream) {
    const float* x   = (const float*)d_in[0];
    const float* adj = (const float*)d_in[1];
    const float* W   = (const float*)d_in[2];
    const float* W2  = (const float*)d_in[3];
    float* out = (float*)d_out;

    char* ws = (char*)d_ws;
    unsigned short* Yt      = (unsigned short*)ws;               // 7,864,320 B
    unsigned short* partial = (unsigned short*)(ws + 7864320);   // 4,194,304 B

    k1_ygemm<<<960, 256, 0, stream>>>(x, W, Yt);
    k2_main <<<512, 512, 0, stream>>>(adj, Yt, partial);
    k3_epi  <<<64,  256, 0, stream>>>(partial, x, W2, out);
}